// Round 3
// baseline (3544.984 us; speedup 1.0000x reference)
//
#include <hip/hip_runtime.h>

#define T_LEN 512
#define NB    32
#define HID4  1024
#define DSTR  ((size_t)T_LEN * NB * HID4)   // per-direction xg stride (elements)

typedef short  bf16x8 __attribute__((ext_vector_type(8)));
typedef float  f32x4  __attribute__((ext_vector_type(4)));

static __device__ __forceinline__ unsigned short f2bf(float f) {
  union { float f; unsigned int i; } v; v.f = f;
  unsigned int r = v.i + 0x7FFFu + ((v.i >> 16) & 1u);
  return (unsigned short)(r >> 16);
}
static __device__ __forceinline__ unsigned short f2h(float f) {
  union { _Float16 h; unsigned short u; } v; v.h = (_Float16)f; return v.u;
}
static __device__ __forceinline__ float h2f(unsigned short u) {
  union { unsigned short u; _Float16 h; } v; v.u = u; return (float)v.h;
}
static __device__ __forceinline__ float sigm(float x) {
  return __builtin_amdgcn_rcpf(1.0f + __builtin_amdgcn_exp2f(-1.44269504f * x));
}
static __device__ __forceinline__ float tanh_fast(float x) {
  float e = __builtin_amdgcn_exp2f(2.885390082f * x);
  return 1.0f - 2.0f * __builtin_amdgcn_rcpf(e + 1.0f);
}
// convert 8 consecutive f32 -> bf16x8
static __device__ __forceinline__ bf16x8 cvt8(const float* p) {
  bf16x8 r;
  #pragma unroll
  for (int i = 0; i < 8; ++i) r[i] = (short)f2bf(p[i]);
  return r;
}

// ---------------------------------------------------------------------------
// GEMM: out[dir][t][b][g] (f16) = sum_k A[b*T+t][k] * W[g][k] + bias[g]
// A: f32 [16384][K], W: f32 [1024][K]. 64x64 tile, 4 waves, K-chunks of 32.
// Staging converts f32 -> bf16 in registers, LDS holds bf16 tiles.
// ---------------------------------------------------------------------------
__global__ __launch_bounds__(256) void gemm_xg(
    const float* __restrict__ A,
    const float* __restrict__ Wf,
    const float* __restrict__ Wb,
    const float* __restrict__ biasf,
    const float* __restrict__ biasb,
    unsigned short* __restrict__ out, int K)
{
  __shared__ __align__(16) unsigned short As[64][40];  // pad 32->40: 2-way only
  __shared__ __align__(16) unsigned short Bs[64][40];

  const int dir = blockIdx.z;
  const float* W    = dir ? Wb    : Wf;
  const float* bias = dir ? biasb : biasf;
  unsigned short* outd = out + (size_t)dir * DSTR;

  const int m0 = blockIdx.x * 64;
  const int n0 = blockIdx.y * 64;
  const int tid = threadIdx.x;
  const int wv = tid >> 6, lane = tid & 63;
  const int lm = lane & 15, lq = lane >> 4;
  const int mt0 = (wv >> 1) * 32, nt0 = (wv & 1) * 32;
  const int lr = tid >> 2, ls = tid & 3;

  f32x4 acc[2][2];
  #pragma unroll
  for (int a = 0; a < 2; ++a)
    #pragma unroll
    for (int b = 0; b < 2; ++b) acc[a][b] = (f32x4){0.f, 0.f, 0.f, 0.f};

  for (int kc = 0; kc < K; kc += 32) {
    *(bf16x8*)&As[lr][ls * 8] = cvt8(A + (size_t)(m0 + lr) * K + kc + ls * 8);
    *(bf16x8*)&Bs[lr][ls * 8] = cvt8(W + (size_t)(n0 + lr) * K + kc + ls * 8);
    __syncthreads();
    bf16x8 af[2], bfr[2];
    af[0]  = *(const bf16x8*)&As[mt0 + lm][lq * 8];
    af[1]  = *(const bf16x8*)&As[mt0 + 16 + lm][lq * 8];
    bfr[0] = *(const bf16x8*)&Bs[nt0 + lm][lq * 8];
    bfr[1] = *(const bf16x8*)&Bs[nt0 + 16 + lm][lq * 8];
    #pragma unroll
    for (int mt = 0; mt < 2; ++mt)
      #pragma unroll
      for (int nt = 0; nt < 2; ++nt)
        acc[mt][nt] = __builtin_amdgcn_mfma_f32_16x16x32_bf16(af[mt], bfr[nt], acc[mt][nt], 0, 0, 0);
    __syncthreads();
  }

  #pragma unroll
  for (int nt = 0; nt < 2; ++nt) {
    const int n = n0 + nt0 + nt * 16 + lm;
    const float bv = bias[n];
    #pragma unroll
    for (int mt = 0; mt < 2; ++mt)
      #pragma unroll
      for (int r = 0; r < 4; ++r) {
        const int m = m0 + mt0 + mt * 16 + lq * 4 + r;
        // token m = b*T + t  ->  out[t][b][g]  (f16)
        outd[((size_t)(m & 511) * NB + (m >> 9)) * HID4 + n] = f2h(acc[mt][nt][r] + bv);
      }
  }
}

// ---------------------------------------------------------------------------
// Recurrence. Grid = 4 blocks (dir*2 + batch-half), 512 threads (8 waves).
// Each wave owns hidden slice [wave*32, wave*32+32): its i,f,g,o gate rows.
// W_hh (f32 in HBM) converted once to bf16 fragments: K-tiles 0..5 in VGPRs,
// 6..7 in LDS (128 KB). h double-buffered in LDS (pitch 264 -> 2-way only).
// c register-resident f32. One __syncthreads per timestep. out written f32.
// ---------------------------------------------------------------------------
__global__ __launch_bounds__(512, 2) void lstm_rec(
    const unsigned short* __restrict__ xg,   // [2][T][32][1024] f16
    const float* __restrict__ whh_f,         // [1024][256] f32
    const float* __restrict__ whh_b,
    float* __restrict__ out)                 // [32][T][512] f32, col off dir*256
{
  extern __shared__ char smem[];
  unsigned short* ldsB = (unsigned short*)smem;             // 128 tiles * 64 lanes * 8 bf16
  unsigned short* hbuf = (unsigned short*)(smem + 131072);  // [2][16][264]

  const int dir = blockIdx.x >> 1, bh = blockIdx.x & 1;
  const int b0 = bh * 16;
  const float* whh = dir ? whh_b : whh_f;
  const unsigned short* xgd = xg + (size_t)dir * DSTR;
  const int wave = threadIdx.x >> 6, lane = threadIdx.x & 63;
  const int lm = lane & 15, lq = lane >> 4;
  const int j0 = wave * 32;

  // ---- preload W_hh fragments (B-operand: n = lane&15, k = lq*8 + j) ----
  bf16x8 breg[4][2][6];
  #pragma unroll
  for (int gt = 0; gt < 4; ++gt)
    #pragma unroll
    for (int nh = 0; nh < 2; ++nh) {
      const float* wrow = whh + (size_t)(gt * 256 + j0 + nh * 16 + lm) * 256;
      #pragma unroll
      for (int kt = 0; kt < 6; ++kt)
        breg[gt][nh][kt] = cvt8(wrow + kt * 32 + lq * 8);
      #pragma unroll
      for (int kt = 6; kt < 8; ++kt) {
        const int tl = wave * 16 + gt * 4 + nh * 2 + (kt - 6);
        *(bf16x8*)(ldsB + ((size_t)tl * 64 + lane) * 8) = cvt8(wrow + kt * 32 + lq * 8);
      }
    }
  for (int i = threadIdx.x; i < 2 * 16 * 264; i += 512) hbuf[i] = 0;
  float creg[2][4] = {{0.f, 0.f, 0.f, 0.f}, {0.f, 0.f, 0.f, 0.f}};
  __syncthreads();

  for (int s = 0; s < T_LEN; ++s) {
    const int tt = dir ? (T_LEN - 1 - s) : s;
    const unsigned short* xgt = xgd + (size_t)tt * NB * HID4;
    const unsigned short* hr = hbuf + (s & 1) * (16 * 264);
    unsigned short* hw = hbuf + ((s + 1) & 1) * (16 * 264);

    #pragma unroll
    for (int nh = 0; nh < 2; ++nh) {
      const int jb = j0 + nh * 16 + lm;  // hidden index within 256
      // issue xg loads; consumed only after the MFMA block -> latency hidden
      unsigned short xgv[4][4];
      #pragma unroll
      for (int gt = 0; gt < 4; ++gt)
        #pragma unroll
        for (int r = 0; r < 4; ++r)
          xgv[gt][r] = xgt[(size_t)(b0 + lq * 4 + r) * HID4 + gt * 256 + jb];

      f32x4 acc[4];
      #pragma unroll
      for (int gt = 0; gt < 4; ++gt) acc[gt] = (f32x4){0.f, 0.f, 0.f, 0.f};

      #pragma unroll
      for (int kt = 0; kt < 8; ++kt) {
        const bf16x8 afrag = *(const bf16x8*)(hr + lm * 264 + kt * 32 + lq * 8);
        #pragma unroll
        for (int gt = 0; gt < 4; ++gt) {
          bf16x8 bfr;
          if (kt < 6) bfr = breg[gt][nh][kt];
          else        bfr = *(const bf16x8*)(ldsB + ((size_t)(wave * 16 + gt * 4 + nh * 2 + (kt - 6)) * 64 + lane) * 8);
          acc[gt] = __builtin_amdgcn_mfma_f32_16x16x32_bf16(afrag, bfr, acc[gt], 0, 0, 0);
        }
      }

      #pragma unroll
      for (int r = 0; r < 4; ++r) {
        const float iv = sigm(acc[0][r] + h2f(xgv[0][r]));
        const float fv = sigm(acc[1][r] + h2f(xgv[1][r]));
        const float gv = tanh_fast(acc[2][r] + h2f(xgv[2][r]));
        const float ov = sigm(acc[3][r] + h2f(xgv[3][r]));
        const float cv = fv * creg[nh][r] + iv * gv;
        creg[nh][r] = cv;
        const float hv = ov * tanh_fast(cv);
        hw[(lq * 4 + r) * 264 + jb] = f2bf(hv);
        out[((size_t)(b0 + lq * 4 + r) * T_LEN + tt) * 512 + dir * 256 + jb] = hv;
      }
    }
    __syncthreads();
  }
}

// ---------------------------------------------------------------------------
extern "C" void kernel_launch(void* const* d_in, const int* in_sizes, int n_in,
                              void* d_out, int out_size, void* d_ws, size_t ws_size,
                              hipStream_t stream) {
  const float* x     = (const float*)d_in[0];
  const float* wih0f = (const float*)d_in[1];
  const float* whh0f = (const float*)d_in[2];
  const float* b0f   = (const float*)d_in[3];
  const float* wih0b = (const float*)d_in[4];
  const float* whh0b = (const float*)d_in[5];
  const float* b0b   = (const float*)d_in[6];
  const float* wih1f = (const float*)d_in[7];
  const float* whh1f = (const float*)d_in[8];
  const float* b1f   = (const float*)d_in[9];
  const float* wih1b = (const float*)d_in[10];
  const float* whh1b = (const float*)d_in[11];
  const float* b1b   = (const float*)d_in[12];
  float* out = (float*)d_out;

  // ws: xg only — [2][T][32][1024] f16 = 64 MiB. Layer-0 hidden states are
  // routed through d_out (f32, same shape as final output; fully overwritten
  // by the layer-1 recurrence afterwards).
  unsigned short* xg = (unsigned short*)d_ws;

  const int REC_LDS = 131072 + 2 * 16 * 264 * 2;  // 147968 B
  hipFuncSetAttribute((const void*)lstm_rec, hipFuncAttributeMaxDynamicSharedMemorySize, REC_LDS);

  gemm_xg<<<dim3(256, 16, 2), 256, 0, stream>>>(x,   wih0f, wih0b, b0f, b0b, xg, 256);
  lstm_rec<<<4, 512, REC_LDS, stream>>>(xg, whh0f, whh0b, out);   // h1 -> d_out (f32)
  gemm_xg<<<dim3(256, 16, 2), 256, 0, stream>>>(out, wih1f, wih1b, b1f, b1b, xg, 512);
  lstm_rec<<<4, 512, REC_LDS, stream>>>(xg, whh1f, whh1b, out);
}

// Round 4
// 3232.412 us; speedup vs baseline: 1.0967x; 1.0967x over previous
//
#include <hip/hip_runtime.h>

#define T_LEN 512
#define NB    32
#define HID4  1024
#define DSTR  ((size_t)T_LEN * NB * HID4)   // per-direction xg stride (elements)

typedef short  bf16x8 __attribute__((ext_vector_type(8)));
typedef float  f32x4  __attribute__((ext_vector_type(4)));

static __device__ __forceinline__ unsigned short f2bf(float f) {
  union { float f; unsigned int i; } v; v.f = f;
  unsigned int r = v.i + 0x7FFFu + ((v.i >> 16) & 1u);
  return (unsigned short)(r >> 16);
}
static __device__ __forceinline__ unsigned short f2h(float f) {
  union { _Float16 h; unsigned short u; } v; v.h = (_Float16)f; return v.u;
}
static __device__ __forceinline__ float h2f(unsigned short u) {
  union { unsigned short u; _Float16 h; } v; v.u = u; return (float)v.h;
}
static __device__ __forceinline__ float sigm(float x) {
  return __builtin_amdgcn_rcpf(1.0f + __builtin_amdgcn_exp2f(-1.44269504f * x));
}
static __device__ __forceinline__ float tanh_fast(float x) {
  float e = __builtin_amdgcn_exp2f(2.885390082f * x);
  return 1.0f - 2.0f * __builtin_amdgcn_rcpf(e + 1.0f);
}
// convert 8 consecutive f32 -> bf16x8
static __device__ __forceinline__ bf16x8 cvt8(const float* p) {
  bf16x8 r;
  #pragma unroll
  for (int i = 0; i < 8; ++i) r[i] = (short)f2bf(p[i]);
  return r;
}
// opaque touch: forbids rematerialization of the value from memory
static __device__ __forceinline__ void pin(bf16x8& x) {
  f32x4 t = __builtin_bit_cast(f32x4, x);
  asm volatile("" : "+v"(t));
  x = __builtin_bit_cast(bf16x8, t);
}

// ---------------------------------------------------------------------------
// GEMM: xg = A @ W^T + bias, written in the rec-thread-swizzled layout:
//   xg[dir][t][bh][tid(512)][c(32)]  (f16), c = nh*16 + gt*4 + r
// so each rec thread reads its 32 per-step values as 4 contiguous 16B loads.
// A: f32 [16384][K], W: f32 [1024][K]. 64x64 tile, 4 waves, K-chunks of 32.
// ---------------------------------------------------------------------------
__global__ __launch_bounds__(256) void gemm_xg(
    const float* __restrict__ A,
    const float* __restrict__ Wf,
    const float* __restrict__ Wb,
    const float* __restrict__ biasf,
    const float* __restrict__ biasb,
    unsigned short* __restrict__ out, int K)
{
  __shared__ __align__(16) unsigned short As[64][40];  // pad 32->40: 2-way only
  __shared__ __align__(16) unsigned short Bs[64][40];

  const int dir = blockIdx.z;
  const float* W    = dir ? Wb    : Wf;
  const float* bias = dir ? biasb : biasf;
  unsigned short* outd = out + (size_t)dir * DSTR;

  const int m0 = blockIdx.x * 64;
  const int n0 = blockIdx.y * 64;
  const int tid = threadIdx.x;
  const int wv = tid >> 6, lane = tid & 63;
  const int lm = lane & 15, lq = lane >> 4;
  const int mt0 = (wv >> 1) * 32, nt0 = (wv & 1) * 32;
  const int lr = tid >> 2, ls = tid & 3;

  f32x4 acc[2][2];
  #pragma unroll
  for (int a = 0; a < 2; ++a)
    #pragma unroll
    for (int b = 0; b < 2; ++b) acc[a][b] = (f32x4){0.f, 0.f, 0.f, 0.f};

  for (int kc = 0; kc < K; kc += 32) {
    *(bf16x8*)&As[lr][ls * 8] = cvt8(A + (size_t)(m0 + lr) * K + kc + ls * 8);
    *(bf16x8*)&Bs[lr][ls * 8] = cvt8(W + (size_t)(n0 + lr) * K + kc + ls * 8);
    __syncthreads();
    bf16x8 af[2], bfr[2];
    af[0]  = *(const bf16x8*)&As[mt0 + lm][lq * 8];
    af[1]  = *(const bf16x8*)&As[mt0 + 16 + lm][lq * 8];
    bfr[0] = *(const bf16x8*)&Bs[nt0 + lm][lq * 8];
    bfr[1] = *(const bf16x8*)&Bs[nt0 + 16 + lm][lq * 8];
    #pragma unroll
    for (int mt = 0; mt < 2; ++mt)
      #pragma unroll
      for (int nt = 0; nt < 2; ++nt)
        acc[mt][nt] = __builtin_amdgcn_mfma_f32_16x16x32_bf16(af[mt], bfr[nt], acc[mt][nt], 0, 0, 0);
    __syncthreads();
  }

  #pragma unroll
  for (int nt = 0; nt < 2; ++nt) {
    const int n = n0 + nt0 + nt * 16 + lm;       // gate index 0..1023
    const float bv = bias[n];
    const int gt = n >> 8, j = n & 255;
    const int wvr = j >> 5, nh = (j >> 4) & 1, lmr = j & 15;
    #pragma unroll
    for (int mt = 0; mt < 2; ++mt)
      #pragma unroll
      for (int r4 = 0; r4 < 4; ++r4) {
        const int m = m0 + mt0 + mt * 16 + lq * 4 + r4;   // token = b*T + t
        const int b = m >> 9, t = m & 511;
        const int bh = b >> 4, lqr = (b >> 2) & 3, rr = b & 3;
        const int tidr = wvr * 64 + lqr * 16 + lmr;
        const int c = nh * 16 + gt * 4 + rr;
        outd[((((size_t)t * 2 + bh) * 512 + tidr) << 5) + c] = f2h(acc[mt][nt][r4] + bv);
      }
  }
}

// ---------------------------------------------------------------------------
// Recurrence. Grid = 4 blocks (dir*2 + batch-half), 512 threads (8 waves).
// Each wave owns hidden slice [wave*32, wave*32+32): its i,f,g,o gate rows.
// W_hh (f32 HBM) -> bf16 fragments: K-tiles 0..5 PINNED in VGPRs (192 regs),
// 6..7 in LDS (128 KB). h double-buffered in LDS (pitch 264 -> ~2-way only).
// xg read as 4x16B per thread per step (swizzled layout). out written f32.
// ---------------------------------------------------------------------------
__global__ __launch_bounds__(512, 2) void lstm_rec(
    const unsigned short* __restrict__ xg,   // [2][T][2][512][32] f16 (swizzled)
    const float* __restrict__ whh_f,         // [1024][256] f32
    const float* __restrict__ whh_b,
    float* __restrict__ out)                 // [32][T][512] f32, col off dir*256
{
  extern __shared__ char smem[];
  unsigned short* ldsB = (unsigned short*)smem;             // 128 tiles * 64 lanes * 8 bf16
  unsigned short* hbuf = (unsigned short*)(smem + 131072);  // [2][16][264]

  const int dir = blockIdx.x >> 1, bh = blockIdx.x & 1;
  const int b0 = bh * 16;
  const float* whh = dir ? whh_b : whh_f;
  const unsigned short* xgd = xg + (size_t)dir * DSTR;
  const int wave = threadIdx.x >> 6, lane = threadIdx.x & 63;
  const int lm = lane & 15, lq = lane >> 4;
  const int j0 = wave * 32;

  // ---- preload W_hh fragments (B-operand: n = lane&15, k = lq*8 + j) ----
  bf16x8 breg[4][2][6];
  #pragma unroll
  for (int gt = 0; gt < 4; ++gt)
    #pragma unroll
    for (int nh = 0; nh < 2; ++nh) {
      const float* wrow = whh + (size_t)(gt * 256 + j0 + nh * 16 + lm) * 256;
      #pragma unroll
      for (int kt = 0; kt < 6; ++kt)
        breg[gt][nh][kt] = cvt8(wrow + kt * 32 + lq * 8);
      #pragma unroll
      for (int kt = 6; kt < 8; ++kt) {
        const int tl = wave * 16 + gt * 4 + nh * 2 + (kt - 6);
        *(bf16x8*)(ldsB + ((size_t)tl * 64 + lane) * 8) = cvt8(wrow + kt * 32 + lq * 8);
      }
    }
  // pin: forbid rematerialization of the 48 fragments (192 VGPRs)
  #pragma unroll
  for (int gt = 0; gt < 4; ++gt)
    #pragma unroll
    for (int nh = 0; nh < 2; ++nh)
      #pragma unroll
      for (int kt = 0; kt < 6; ++kt)
        pin(breg[gt][nh][kt]);

  for (int i = threadIdx.x; i < 2 * 16 * 264; i += 512) hbuf[i] = 0;
  float creg[2][4] = {{0.f, 0.f, 0.f, 0.f}, {0.f, 0.f, 0.f, 0.f}};
  __syncthreads();

  for (int s = 0; s < T_LEN; ++s) {
    const int tt = dir ? (T_LEN - 1 - s) : s;
    const unsigned short* hr = hbuf + (s & 1) * (16 * 264);
    unsigned short* hw = hbuf + ((s + 1) & 1) * (16 * 264);

    // xg: 4 contiguous 16B loads; consumed only after the MFMA block
    const unsigned short* xp = xgd + ((((size_t)tt * 2 + bh) * 512 + threadIdx.x) << 5);
    bf16x8 xq[4];
    #pragma unroll
    for (int q = 0; q < 4; ++q) xq[q] = *(const bf16x8*)(xp + q * 8);

    #pragma unroll
    for (int nh = 0; nh < 2; ++nh) {
      const int jb = j0 + nh * 16 + lm;  // hidden index within 256

      f32x4 acc[4];
      #pragma unroll
      for (int gt = 0; gt < 4; ++gt) acc[gt] = (f32x4){0.f, 0.f, 0.f, 0.f};

      #pragma unroll
      for (int kt = 0; kt < 8; ++kt) {
        const bf16x8 afrag = *(const bf16x8*)(hr + lm * 264 + kt * 32 + lq * 8);
        #pragma unroll
        for (int gt = 0; gt < 4; ++gt) {
          bf16x8 bfr;
          if (kt < 6) bfr = breg[gt][nh][kt];
          else        bfr = *(const bf16x8*)(ldsB + ((size_t)(wave * 16 + gt * 4 + nh * 2 + (kt - 6)) * 64 + lane) * 8);
          acc[gt] = __builtin_amdgcn_mfma_f32_16x16x32_bf16(afrag, bfr, acc[gt], 0, 0, 0);
        }
      }

      #pragma unroll
      for (int r = 0; r < 4; ++r) {
        // xg value for (nh,gt,r) lives in xq[nh*2+(gt>>1)][(gt&1)*4+r]
        const float x0 = h2f((unsigned short)xq[nh * 2 + 0][0 * 4 + r]);
        const float x1 = h2f((unsigned short)xq[nh * 2 + 0][1 * 4 + r]);
        const float x2 = h2f((unsigned short)xq[nh * 2 + 1][0 * 4 + r]);
        const float x3 = h2f((unsigned short)xq[nh * 2 + 1][1 * 4 + r]);
        const float iv = sigm(acc[0][r] + x0);
        const float fv = sigm(acc[1][r] + x1);
        const float gv = tanh_fast(acc[2][r] + x2);
        const float ov = sigm(acc[3][r] + x3);
        const float cv = fv * creg[nh][r] + iv * gv;
        creg[nh][r] = cv;
        const float hv = ov * tanh_fast(cv);
        hw[(lq * 4 + r) * 264 + jb] = f2bf(hv);
        out[((size_t)(b0 + lq * 4 + r) * T_LEN + tt) * 512 + dir * 256 + jb] = hv;
      }
    }
    __syncthreads();
  }
}

// ---------------------------------------------------------------------------
extern "C" void kernel_launch(void* const* d_in, const int* in_sizes, int n_in,
                              void* d_out, int out_size, void* d_ws, size_t ws_size,
                              hipStream_t stream) {
  const float* x     = (const float*)d_in[0];
  const float* wih0f = (const float*)d_in[1];
  const float* whh0f = (const float*)d_in[2];
  const float* b0f   = (const float*)d_in[3];
  const float* wih0b = (const float*)d_in[4];
  const float* whh0b = (const float*)d_in[5];
  const float* b0b   = (const float*)d_in[6];
  const float* wih1f = (const float*)d_in[7];
  const float* whh1f = (const float*)d_in[8];
  const float* b1f   = (const float*)d_in[9];
  const float* wih1b = (const float*)d_in[10];
  const float* whh1b = (const float*)d_in[11];
  const float* b1b   = (const float*)d_in[12];
  float* out = (float*)d_out;

  // ws: xg only — [2][T][2][512][32] f16 = 64 MiB. Layer-0 hidden states are
  // routed through d_out (f32, fully overwritten by the layer-1 recurrence).
  unsigned short* xg = (unsigned short*)d_ws;

  const int REC_LDS = 131072 + 2 * 16 * 264 * 2;  // 147968 B
  hipFuncSetAttribute((const void*)lstm_rec, hipFuncAttributeMaxDynamicSharedMemorySize, REC_LDS);

  gemm_xg<<<dim3(256, 16, 2), 256, 0, stream>>>(x,   wih0f, wih0b, b0f, b0b, xg, 256);
  lstm_rec<<<4, 512, REC_LDS, stream>>>(xg, whh0f, whh0b, out);   // h1 -> d_out (f32)
  gemm_xg<<<dim3(256, 16, 2), 256, 0, stream>>>(out, wih1f, wih1b, b1f, b1b, xg, 512);
  lstm_rec<<<4, 512, REC_LDS, stream>>>(xg, whh1f, whh1b, out);
}